// Round 1
// baseline (99.068 us; speedup 1.0000x reference)
//
#include <hip/hip_runtime.h>

#define TGT 100
#define SRC 100
#define KDIM 512
#define HH 256
#define ROWS 1600              // BS*100
#define LOG2E2 2.8853900817779268f   // 2/ln(2): e^(2x) = 2^(LOG2E2*x)

typedef __attribute__((ext_vector_type(8))) short bf16x8;
typedef __attribute__((ext_vector_type(4))) float f32x4;

// ws layout: floats [Ek 409600][EqT 409600]  (Apk/Bpk eliminated in R7 fusion)
#define EQT_OFF 409600

static __device__ __forceinline__ short f2b(float f) {
    union { float f; unsigned u; } v; v.f = f;
    return (short)((v.u + 0x7FFFu + ((v.u >> 16) & 1u)) >> 16);
}

// ---------------------------------------------------------------------------
// R7: prep fused into the GEMM. Block = (rtg, ht): 4 waves share ONE ht
// (B fragment staged once per block into 16 KB LDS), each wave owns row-tile
// rt = rtg*4+wv and converts its A-stream fp32->bf16 inline (coalesced
// f32x4 pairs + 8 f2b per kk — ~noise vs. MFMA). Eliminates the prep
// dispatch, its graph drain, and the Apk/Bpk workspace round-trip.
//   rtg 0..24  -> rt 0..99   : Ek [b*100+s][h]  = exp2(L * keys@Wk)
//   rtg 25..49 -> rt 100..199: EqT[h][b*100+t]  = exp2(L * (query@Wq + b1))
// Fragment layouts identical to the R6 prep (m89/m92-verified):
//   A[m=lane&15][k=kk*32+(lane>>4)*8+j],  B=W[k][ht*16+(lane&15)]
// D layout: col=lane&15, row=(lane>>4)*4+reg.
// NOTE (R6): do NOT fuse gemm+score behind a device-scope grid barrier —
// agent-scope fence/acquire at 800 blocks = per-XCD L2 wb/inv storm, 317 us.
// ---------------------------------------------------------------------------
__global__ __launch_bounds__(256) void gemm_exp_fused(
    const float* __restrict__ query, const float* __restrict__ keys,
    const float* __restrict__ Wk, const float* __restrict__ Wq,
    const float* __restrict__ b1,
    float* __restrict__ Ek, float* __restrict__ EqT)
{
    __shared__ short Bf[8192];           // [kk][lane][8] bf16 fragments, 16 KB
    const int tid  = threadIdx.x;
    const int lane = tid & 63;
    const int wv   = tid >> 6;
    const int bx   = blockIdx.x;         // 0..799
    const int rtg  = bx >> 4;            // 0..49 (4 row-tiles each)
    const int ht   = bx & 15;
    const int isq  = rtg >= 25;          // block-uniform
    const float* __restrict__ W = isq ? Wq : Wk;

    // ---- stage B(ht) fragments into LDS, once per block ----
    // fragment f = kk*64 + ln; value = W[kk*32+(ln>>4)*8+j][ht*16+(ln&15)].
    // Loads: 16 lanes x 64B contiguous per group -> 4 segments/instr.
    // ds_write_b128 contiguous 1KB/wave -> conflict-free.
    #pragma unroll
    for (int i = 0; i < 4; ++i) {
        const int f  = tid + 256 * i;
        const int kk = f >> 6;
        const int ln = f & 63;
        const float* wp = W + (size_t)(kk * 32 + (ln >> 4) * 8) * HH
                            + ht * 16 + (ln & 15);
        bf16x8 v;
        #pragma unroll
        for (int j = 0; j < 8; ++j) v[j] = f2b(wp[(size_t)j * HH]);
        *(bf16x8*)(Bf + (size_t)f * 8) = v;
    }
    __syncthreads();

    // ---- per-wave GEMM over K=512: inline A cvt + LDS B + MFMA ----
    const int rt = rtg * 4 + wv;         // 0..199
    const int rl = isq ? rt - 100 : rt;  // 0..99 row-tile within its matrix
    const float* __restrict__ A = isq ? query : keys;
    const float* arow = A + (size_t)(rl * 16 + (lane & 15)) * KDIM
                          + (lane >> 4) * 8;
    const short* bfp = Bf + lane * 8;

    f32x4 acc = {0.f, 0.f, 0.f, 0.f};
    #pragma unroll
    for (int kk = 0; kk < 16; ++kk) {
        f32x4 a0 = *(const f32x4*)(arow + kk * 32);
        f32x4 a1 = *(const f32x4*)(arow + kk * 32 + 4);
        bf16x8 af;
        #pragma unroll
        for (int j = 0; j < 4; ++j) { af[j] = f2b(a0[j]); af[j + 4] = f2b(a1[j]); }
        bf16x8 bfr = *(const bf16x8*)(bfp + (size_t)kk * 512);
        acc = __builtin_amdgcn_mfma_f32_16x16x32_bf16(af, bfr, acc, 0, 0, 0);
    }

    const int m = lane & 15, q = lane >> 4;
    const int hc = ht * 16 + m;
    const int r0 = rl * 16;
    if (!isq) {
        #pragma unroll
        for (int r = 0; r < 4; ++r) {
            const int row = r0 + q * 4 + r;
            Ek[(size_t)row * HH + hc] = __builtin_amdgcn_exp2f(LOG2E2 * acc[r]);
        }
    } else {
        const float bb = b1[hc];
        #pragma unroll
        for (int r = 0; r < 4; ++r) {
            const int row = r0 + q * 4 + r;
            EqT[(size_t)hc * ROWS + row] =
                __builtin_amdgcn_exp2f(LOG2E2 * (acc[r] + bb));
        }
    }
}

// ---------------------------------------------------------------------------
// Score: score[b][s][t] = tanh(sumW2 - 2*sum_h W2[h]/(Ek[s,h]*Eq[t,h]+1) + b2)
// Block (256 thr) = (b, s-QUAD, 64-t-chunk); each of 4 waves takes a 64-h
// quarter for all 4 s. Per iter: 7 loads covering 512 (s,t,h) elems.
// 4KB LDS reduce; wave w emits output row s0+w. grid = 16*25*2 = 800 blocks.
// (unchanged from R6 for attribution)
// ---------------------------------------------------------------------------
__global__ __launch_bounds__(256) void score_kernel(
    const float* __restrict__ Ek, const float* __restrict__ EqT,
    const float* __restrict__ W2, const float* __restrict__ B2,
    float* __restrict__ out)
{
    __shared__ float red[4][4][64];
    const int lane = threadIdx.x & 63;
    const int wv = threadIdx.x >> 6;
    const int bx = blockIdx.x;           // 0..799
    const int tc = (bx & 1) << 6;        // 0 or 64
    const int g  = bx >> 1;              // 0..399
    const int sq = g % 25;
    const int b  = g / 25;
    const int s0 = sq * 4;
    const int t  = tc + lane;
    const int tcl = t < TGT ? t : TGT - 1;
    const int h0 = wv * 64;

    const float* __restrict__ ek = Ek + (size_t)(b * SRC + s0) * HH + h0;
    const float* __restrict__ eq = EqT + (size_t)h0 * ROWS + (size_t)b * TGT + tcl;
    const float* __restrict__ w2 = W2 + h0;

    float acc0 = 0.f, acc1 = 0.f, acc2 = 0.f, acc3 = 0.f;
    #pragma unroll 4
    for (int hp = 0; hp < 32; ++hp) {
        const int h = hp * 2;
        const float2 w  = *(const float2*)(w2 + h);
        const float  e0 = eq[(size_t)h * ROWS];
        const float  e1 = eq[(size_t)(h + 1) * ROWS];
        const float2 k0 = *(const float2*)(ek + h);
        const float2 k1 = *(const float2*)(ek + HH + h);
        const float2 k2 = *(const float2*)(ek + 2 * HH + h);
        const float2 k3 = *(const float2*)(ek + 3 * HH + h);
        acc0 = fmaf(w.x, __builtin_amdgcn_rcpf(fmaf(k0.x, e0, 1.f)), acc0);
        acc1 = fmaf(w.x, __builtin_amdgcn_rcpf(fmaf(k1.x, e0, 1.f)), acc1);
        acc2 = fmaf(w.x, __builtin_amdgcn_rcpf(fmaf(k2.x, e0, 1.f)), acc2);
        acc3 = fmaf(w.x, __builtin_amdgcn_rcpf(fmaf(k3.x, e0, 1.f)), acc3);
        acc0 = fmaf(w.y, __builtin_amdgcn_rcpf(fmaf(k0.y, e1, 1.f)), acc0);
        acc1 = fmaf(w.y, __builtin_amdgcn_rcpf(fmaf(k1.y, e1, 1.f)), acc1);
        acc2 = fmaf(w.y, __builtin_amdgcn_rcpf(fmaf(k2.y, e1, 1.f)), acc2);
        acc3 = fmaf(w.y, __builtin_amdgcn_rcpf(fmaf(k3.y, e1, 1.f)), acc3);
    }
    red[0][wv][lane] = acc0;
    red[1][wv][lane] = acc1;
    red[2][wv][lane] = acc2;
    red[3][wv][lane] = acc3;
    __syncthreads();

    // wave wv emits output row s0+wv at column t
    float a = red[wv][0][lane] + red[wv][1][lane] + red[wv][2][lane] + red[wv][3][lane];
    float sw = W2[lane] + W2[lane + 64] + W2[lane + 128] + W2[lane + 192];
    #pragma unroll
    for (int off = 32; off; off >>= 1) sw += __shfl_xor(sw, off, 64);
    const float x = sw - 2.f * a + B2[0];
    const float gx = __builtin_amdgcn_exp2f(LOG2E2 * x);
    if (t < TGT)
        out[((size_t)b * SRC + s0 + wv) * TGT + t] =
            1.f - 2.f * __builtin_amdgcn_rcpf(gx + 1.f);
}

extern "C" void kernel_launch(void* const* d_in, const int* in_sizes, int n_in,
                              void* d_out, int out_size, void* d_ws, size_t ws_size,
                              hipStream_t stream) {
    const float* query = (const float*)d_in[0];
    const float* keys  = (const float*)d_in[1];
    const float* Wk    = (const float*)d_in[2];
    const float* Wq    = (const float*)d_in[3];
    const float* b1    = (const float*)d_in[4];
    const float* W2    = (const float*)d_in[5];
    const float* B2    = (const float*)d_in[6];
    float* out = (float*)d_out;

    float* Ek  = (float*)d_ws;
    float* EqT = Ek + EQT_OFF;

    gemm_exp_fused<<<800, 256, 0, stream>>>(query, keys, Wk, Wq, b1, Ek, EqT);
    score_kernel<<<800, 256, 0, stream>>>(Ek, EqT, W2, B2, out);
}

// Round 2
// 91.115 us; speedup vs baseline: 1.0873x; 1.0873x over previous
//
#include <hip/hip_runtime.h>

#define TGT 100
#define SRC 100
#define KDIM 512
#define HH 256
#define ROWS 1600              // BS*100
#define LOG2E2 2.8853900817779268f   // 2/ln(2): e^(2x) = 2^(LOG2E2*x)

typedef __attribute__((ext_vector_type(8))) short bf16x8;
typedef __attribute__((ext_vector_type(4))) float f32x4;

// ws layout: floats [Ek 409600][EqT 409600] then shorts [Apk 1638400][Bpk 262144]
#define EQT_OFF 409600
#define PK_FLOAT_OFF 819200
#define APK_SHORTS 1638400     // 2 mats * 100 rt * 16 kk * 64 lane * 8

static __device__ __forceinline__ short f2b(float f) {
    union { float f; unsigned u; } v; v.f = f;
    return (short)((v.u + 0x7FFFu + ((v.u >> 16) & 1u)) >> 16);
}

// ---------------------------------------------------------------------------
// Prep: one-shot fp32->bf16 conversion into MFMA-fragment-contiguous layouts.
// Apk[(mat*100+rt)*16+kk][lane][8] : A[m=lane&15][k=kk*32+(lane>>4)*8+j]
// Bpk[(mat*16+ht)*16+kk][lane][8]  : W[k=kk*32+(lane>>4)*8+j][ht*16+(lane&15)]
// Pays the strided W gather + cvt ONCE.
// NOTE (R6): do NOT fuse phases behind a device-scope grid barrier —
// agent-scope fence/acquire at 800 blocks = per-XCD L2 wb/inv storm, 317 us.
// NOTE (R7): do NOT fuse prep into gemm either — per-block W re-gather is a
// 25x strided-load amplification, +6 us (99.1 vs 93.3 measured).
// ---------------------------------------------------------------------------
__global__ __launch_bounds__(256) void prep_kernel(
    const float* __restrict__ query, const float* __restrict__ keys,
    const float* __restrict__ Wk, const float* __restrict__ Wq,
    short* __restrict__ Apk, short* __restrict__ Bpk)
{
    const int tid = blockIdx.x * 256 + threadIdx.x;
    if (tid < 204800) {                       // A-pack: (mat,rt,kk,lane)
        const int lane = tid & 63;
        const int rest = tid >> 6;            // (mat*100+rt)*16 + kk
        const int kk = rest & 15;
        const int rg = rest >> 4;             // mat*100+rt, 0..199
        const float* A = (rg >= 100) ? query : keys;
        const int r = (rg % 100) * 16 + (lane & 15);
        const int kb = kk * 32 + (lane >> 4) * 8;
        const float* src = A + (size_t)r * KDIM + kb;
        f32x4 a0 = *(const f32x4*)src;
        f32x4 a1 = *(const f32x4*)(src + 4);
        bf16x8 v;
        #pragma unroll
        for (int j = 0; j < 4; ++j) { v[j] = f2b(a0[j]); v[j + 4] = f2b(a1[j]); }
        *(bf16x8*)(Apk + (size_t)tid * 8) = v;
    } else if (tid < 237568) {                // B-pack: (mat,ht,kk,lane)
        const int t2 = tid - 204800;
        const int lane = t2 & 63;
        const int rest = t2 >> 6;             // (mat*16+ht)*16 + kk
        const int kk = rest & 15;
        const int ht = (rest >> 4) & 15;
        const float* W = (rest >> 8) ? Wq : Wk;
        const int kb = kk * 32 + (lane >> 4) * 8;
        const int col = ht * 16 + (lane & 15);
        const float* wp = W + (size_t)kb * HH + col;
        bf16x8 v;
        #pragma unroll
        for (int j = 0; j < 8; ++j) v[j] = f2b(wp[(size_t)j * HH]);
        *(bf16x8*)(Bpk + (size_t)t2 * 8) = v;
    }
}

// ---------------------------------------------------------------------------
// GEMM+exp (R8): 1 wave per ht-PAIR of 16x16 C-tiles — wave w owns row-tile
// rt = w>>3 and columns ht = (w&7) and (w&7)+8. One A-fragment stream feeds
// two MFMAs into two independent accumulators: halves Apk L2 re-read
// (26->13 MB), 2x MFMA ILP (two independent 16-deep chains), half the waves.
// Per-tile accumulation order is IDENTICAL to R6 -> bit-identical numerics.
//   rt 0..99   : Ek [b*100+s][h]  = exp2(L * keys@Wk)
//   rt 100..199: EqT[h][b*100+t]  = exp2(L * (query@Wq + b1))  (transposed)
// D layout: col=lane&15, row=(lane>>4)*4+reg  (m89/m92-verified).
// grid = 400 blocks * 4 waves = 1600 waves.
// ---------------------------------------------------------------------------
__global__ __launch_bounds__(256) void gemm_exp_kernel(
    const short* __restrict__ Apk, const short* __restrict__ Bpk,
    const float* __restrict__ b1,
    float* __restrict__ Ek, float* __restrict__ EqT)
{
    const int lane = threadIdx.x & 63;
    const int w = blockIdx.x * 4 + (threadIdx.x >> 6);   // 0..1599
    const int rt = w >> 3;               // 0..199 == mat*100 + rtl
    const int htp = w & 7;               // ht pair: htp, htp+8
    const int isq = rt >= 100;
    const short* ap = Apk + ((size_t)(rt * 16) * 64 + lane) * 8;
    const short* bp0 = Bpk + ((size_t)((isq * 16 + htp) * 16) * 64 + lane) * 8;
    const short* bp1 = bp0 + (size_t)8 * 16 * 64 * 8;    // ht+8 stream

    f32x4 acc0 = {0.f, 0.f, 0.f, 0.f};
    f32x4 acc1 = {0.f, 0.f, 0.f, 0.f};
    #pragma unroll
    for (int kk = 0; kk < 16; ++kk) {
        bf16x8 af = *(const bf16x8*)(ap + (size_t)kk * 512);
        bf16x8 b0 = *(const bf16x8*)(bp0 + (size_t)kk * 512);
        bf16x8 b1v = *(const bf16x8*)(bp1 + (size_t)kk * 512);
        acc0 = __builtin_amdgcn_mfma_f32_16x16x32_bf16(af, b0, acc0, 0, 0, 0);
        acc1 = __builtin_amdgcn_mfma_f32_16x16x32_bf16(af, b1v, acc1, 0, 0, 0);
    }

    const int m = lane & 15, q = lane >> 4;
    const int hc0 = htp * 16 + m;
    const int hc1 = hc0 + 128;           // (htp+8)*16 + m
    const int r0 = (isq ? rt - 100 : rt) * 16;
    if (!isq) {
        #pragma unroll
        for (int r = 0; r < 4; ++r) {
            const int row = r0 + q * 4 + r;
            Ek[(size_t)row * HH + hc0] = __builtin_amdgcn_exp2f(LOG2E2 * acc0[r]);
            Ek[(size_t)row * HH + hc1] = __builtin_amdgcn_exp2f(LOG2E2 * acc1[r]);
        }
    } else {
        const float bb0 = b1[hc0];
        const float bb1 = b1[hc1];
        #pragma unroll
        for (int r = 0; r < 4; ++r) {
            const int row = r0 + q * 4 + r;
            EqT[(size_t)hc0 * ROWS + row] =
                __builtin_amdgcn_exp2f(LOG2E2 * (acc0[r] + bb0));
            EqT[(size_t)hc1 * ROWS + row] =
                __builtin_amdgcn_exp2f(LOG2E2 * (acc1[r] + bb1));
        }
    }
}

// ---------------------------------------------------------------------------
// Score: score[b][s][t] = tanh(sumW2 - 2*sum_h W2[h]/(Ek[s,h]*Eq[t,h]+1) + b2)
// Block (256 thr) = (b, s-QUAD, 64-t-chunk); each of 4 waves takes a 64-h
// quarter for all 4 s. Per iter: 7 loads covering 512 (s,t,h) elems.
// 4KB LDS reduce; wave w emits output row s0+w. grid = 16*25*2 = 800 blocks.
// (unchanged from R6 for attribution)
// ---------------------------------------------------------------------------
__global__ __launch_bounds__(256) void score_kernel(
    const float* __restrict__ Ek, const float* __restrict__ EqT,
    const float* __restrict__ W2, const float* __restrict__ B2,
    float* __restrict__ out)
{
    __shared__ float red[4][4][64];
    const int lane = threadIdx.x & 63;
    const int wv = threadIdx.x >> 6;
    const int bx = blockIdx.x;           // 0..799
    const int tc = (bx & 1) << 6;        // 0 or 64
    const int g  = bx >> 1;              // 0..399
    const int sq = g % 25;
    const int b  = g / 25;
    const int s0 = sq * 4;
    const int t  = tc + lane;
    const int tcl = t < TGT ? t : TGT - 1;
    const int h0 = wv * 64;

    const float* __restrict__ ek = Ek + (size_t)(b * SRC + s0) * HH + h0;
    const float* __restrict__ eq = EqT + (size_t)h0 * ROWS + (size_t)b * TGT + tcl;
    const float* __restrict__ w2 = W2 + h0;

    float acc0 = 0.f, acc1 = 0.f, acc2 = 0.f, acc3 = 0.f;
    #pragma unroll 4
    for (int hp = 0; hp < 32; ++hp) {
        const int h = hp * 2;
        const float2 w  = *(const float2*)(w2 + h);
        const float  e0 = eq[(size_t)h * ROWS];
        const float  e1 = eq[(size_t)(h + 1) * ROWS];
        const float2 k0 = *(const float2*)(ek + h);
        const float2 k1 = *(const float2*)(ek + HH + h);
        const float2 k2 = *(const float2*)(ek + 2 * HH + h);
        const float2 k3 = *(const float2*)(ek + 3 * HH + h);
        acc0 = fmaf(w.x, __builtin_amdgcn_rcpf(fmaf(k0.x, e0, 1.f)), acc0);
        acc1 = fmaf(w.x, __builtin_amdgcn_rcpf(fmaf(k1.x, e0, 1.f)), acc1);
        acc2 = fmaf(w.x, __builtin_amdgcn_rcpf(fmaf(k2.x, e0, 1.f)), acc2);
        acc3 = fmaf(w.x, __builtin_amdgcn_rcpf(fmaf(k3.x, e0, 1.f)), acc3);
        acc0 = fmaf(w.y, __builtin_amdgcn_rcpf(fmaf(k0.y, e1, 1.f)), acc0);
        acc1 = fmaf(w.y, __builtin_amdgcn_rcpf(fmaf(k1.y, e1, 1.f)), acc1);
        acc2 = fmaf(w.y, __builtin_amdgcn_rcpf(fmaf(k2.y, e1, 1.f)), acc2);
        acc3 = fmaf(w.y, __builtin_amdgcn_rcpf(fmaf(k3.y, e1, 1.f)), acc3);
    }
    red[0][wv][lane] = acc0;
    red[1][wv][lane] = acc1;
    red[2][wv][lane] = acc2;
    red[3][wv][lane] = acc3;
    __syncthreads();

    // wave wv emits output row s0+wv at column t
    float a = red[wv][0][lane] + red[wv][1][lane] + red[wv][2][lane] + red[wv][3][lane];
    float sw = W2[lane] + W2[lane + 64] + W2[lane + 128] + W2[lane + 192];
    #pragma unroll
    for (int off = 32; off; off >>= 1) sw += __shfl_xor(sw, off, 64);
    const float x = sw - 2.f * a + B2[0];
    const float gx = __builtin_amdgcn_exp2f(LOG2E2 * x);
    if (t < TGT)
        out[((size_t)b * SRC + s0 + wv) * TGT + t] =
            1.f - 2.f * __builtin_amdgcn_rcpf(gx + 1.f);
}

extern "C" void kernel_launch(void* const* d_in, const int* in_sizes, int n_in,
                              void* d_out, int out_size, void* d_ws, size_t ws_size,
                              hipStream_t stream) {
    const float* query = (const float*)d_in[0];
    const float* keys  = (const float*)d_in[1];
    const float* Wk    = (const float*)d_in[2];
    const float* Wq    = (const float*)d_in[3];
    const float* b1    = (const float*)d_in[4];
    const float* W2    = (const float*)d_in[5];
    const float* B2    = (const float*)d_in[6];
    float* out = (float*)d_out;

    float* Ek  = (float*)d_ws;
    float* EqT = Ek + EQT_OFF;
    short* Apk = (short*)(Ek + PK_FLOAT_OFF);
    short* Bpk = Apk + APK_SHORTS;

    prep_kernel<<<928, 256, 0, stream>>>(query, keys, Wk, Wq, Apk, Bpk);
    gemm_exp_kernel<<<400, 256, 0, stream>>>(Apk, Bpk, b1, Ek, EqT);
    score_kernel<<<800, 256, 0, stream>>>(Ek, EqT, W2, B2, out);
}